// Round 1
// baseline (331.040 us; speedup 1.0000x reference)
//
#include <hip/hip_runtime.h>
#include <hip/hip_bf16.h>
#include <cstdint>

typedef __bf16 bf16;
typedef __bf16 bf16x4 __attribute__((ext_vector_type(4)));
typedef __bf16 bf16x8 __attribute__((ext_vector_type(8)));
typedef float f32x4 __attribute__((ext_vector_type(4)));

#define GK 768   // inner K for both GEMMs
#define LN_EPS 1e-5f
#define NORM_EPS 1e-12f

// ---------------- async global->LDS helper ----------------
__device__ __forceinline__ void gl_lds16(const void* g, void* l) {
  __builtin_amdgcn_global_load_lds(
      (__attribute__((address_space(1))) uint32_t*)(uintptr_t)g,
      (__attribute__((address_space(3))) uint32_t*)(uintptr_t)l,
      16, 0, 0);
}

// ---------------- block reduce (2 values, 256 threads) ----------------
__device__ __forceinline__ void blockReduce2(float& s, float& ss, float* sm) {
  #pragma unroll
  for (int o = 32; o > 0; o >>= 1) {
    s  += __shfl_down(s, o, 64);
    ss += __shfl_down(ss, o, 64);
  }
  int wave = threadIdx.x >> 6, lane = threadIdx.x & 63;
  if (lane == 0) { sm[wave] = s; sm[4 + wave] = ss; }
  __syncthreads();
  s  = sm[0] + sm[1] + sm[2] + sm[3];
  ss = sm[4] + sm[5] + sm[6] + sm[7];
}

// ---------------- 0: tiled transpose + fp32->bf16 ----------------
// w [R][Ncols] fp32  ->  wt [Ncols][R] bf16   (R, Ncols multiples of 32)
__global__ __launch_bounds__(256) void transpose_cvt(const float* __restrict__ w,
                                                     bf16* __restrict__ wt,
                                                     int R, int Ncols) {
  __shared__ float tile[32][33];
  int tx = threadIdx.x & 31, ty = threadIdx.x >> 5;   // 32 x 8
  int c0 = blockIdx.x * 32, r0 = blockIdx.y * 32;
  #pragma unroll
  for (int i = 0; i < 32; i += 8)
    tile[ty + i][tx] = w[(size_t)(r0 + ty + i) * Ncols + (c0 + tx)];
  __syncthreads();
  #pragma unroll
  for (int i = 0; i < 32; i += 8)
    wt[(size_t)(c0 + ty + i) * R + (r0 + tx)] = (bf16)tile[tx][ty + i];
}

// ---------------- 1: input LayerNorm -> bf16 ----------------
__global__ __launch_bounds__(256) void ln_in_kernel(const float* __restrict__ x,
                                                    const float* __restrict__ g,
                                                    const float* __restrict__ b,
                                                    bf16* __restrict__ h) {
  __shared__ float sm[8];
  int row = blockIdx.x, t = threadIdx.x;
  const float* xr = x + (size_t)row * 768;
  float4 v = make_float4(0.f, 0.f, 0.f, 0.f);
  if (t < 192) v = ((const float4*)xr)[t];
  float s  = v.x + v.y + v.z + v.w;
  float ss = v.x * v.x + v.y * v.y + v.z * v.z + v.w * v.w;
  blockReduce2(s, ss, sm);
  float mu  = s * (1.0f / 768.0f);
  float inv = rsqrtf(ss * (1.0f / 768.0f) - mu * mu + LN_EPS);
  if (t < 192) {
    float4 gg = ((const float4*)g)[t];
    float4 bb = ((const float4*)b)[t];
    bf16x4 o;
    o[0] = (bf16)((v.x - mu) * inv * gg.x + bb.x);
    o[1] = (bf16)((v.y - mu) * inv * gg.y + bb.y);
    o[2] = (bf16)((v.z - mu) * inv * gg.z + bb.z);
    o[3] = (bf16)((v.w - mu) * inv * gg.w + bb.w);
    ((bf16x4*)(h + (size_t)row * 768))[t] = o;
  }
}

// ---------------- 2: bf16 GEMM, A[M][768] x Bt[N][768]^T -> C[M][N] ----------------
template <bool OUT_BF16>
__global__ __launch_bounds__(256) void gemm_bt(const bf16* __restrict__ A,
                                               const bf16* __restrict__ Bt,
                                               void* __restrict__ Cv,
                                               int Nn, int NBN) {
  __shared__ __align__(16) bf16 As[128 * 32];
  __shared__ __align__(16) bf16 Bs[128 * 32];
  const int tid  = threadIdx.x;
  const int wave = tid >> 6, lane = tid & 63;
  const int lhi  = lane >> 4, llo = lane & 15;

  // XCD-aware swizzle (grid sizes are multiples of 8)
  const int nwg = gridDim.x, bid = blockIdx.x;
  const int wg  = (bid & 7) * (nwg >> 3) + (bid >> 3);
  const int rb = wg / NBN, cb = wg - rb * NBN;
  const int brow = rb * 128, bcol = cb * 128;
  const int wr = wave >> 1, wc = wave & 1;

  f32x4 acc[4][4];
  #pragma unroll
  for (int m = 0; m < 4; ++m)
    #pragma unroll
    for (int n = 0; n < 4; ++n) acc[m][n] = (f32x4){0.f, 0.f, 0.f, 0.f};

  for (int k0 = 0; k0 < GK; k0 += 32) {
    #pragma unroll
    for (int it = 0; it < 2; ++it) {
      int t = it * 256 + tid;
      int r = t >> 2;            // tile row 0..127
      int c = (t & 3) * 8;       // k offset 0/8/16/24
      gl_lds16(A  + (size_t)(brow + r) * GK + k0 + c, &As[(it * 256 + wave * 64) * 8]);
      gl_lds16(Bt + (size_t)(bcol + r) * GK + k0 + c, &Bs[(it * 256 + wave * 64) * 8]);
    }
    __syncthreads();
    bf16x8 af[4], bfr[4];
    #pragma unroll
    for (int m = 0; m < 4; ++m)
      af[m] = *(const bf16x8*)&As[(wr * 64 + m * 16 + llo) * 32 + lhi * 8];
    #pragma unroll
    for (int n = 0; n < 4; ++n)
      bfr[n] = *(const bf16x8*)&Bs[(wc * 64 + n * 16 + llo) * 32 + lhi * 8];
    #pragma unroll
    for (int m = 0; m < 4; ++m)
      #pragma unroll
      for (int n = 0; n < 4; ++n)
        acc[m][n] = __builtin_amdgcn_mfma_f32_16x16x32_bf16(af[m], bfr[n], acc[m][n], 0, 0, 0);
    __syncthreads();
  }

  #pragma unroll
  for (int m = 0; m < 4; ++m) {
    #pragma unroll
    for (int n = 0; n < 4; ++n) {
      int row = brow + wr * 64 + m * 16 + lhi * 4;
      int col = bcol + wc * 64 + n * 16 + llo;
      #pragma unroll
      for (int r2 = 0; r2 < 4; ++r2) {
        if (OUT_BF16)
          ((bf16*)Cv)[(size_t)(row + r2) * Nn + col] = (bf16)acc[m][n][r2];
        else
          ((float*)Cv)[(size_t)(row + r2) * Nn + col] = acc[m][n][r2];
      }
    }
  }
}

// ---------------- 3a: per-token inverse L2 norms of q and k ----------------
__global__ __launch_bounds__(256) void norm_kernel(const bf16* __restrict__ qkv,
                                                   float* __restrict__ iqn,
                                                   float* __restrict__ ikn) {
  __shared__ float sm[8];
  int row = blockIdx.x, t = threadIdx.x;
  const bf16* qr = qkv + (size_t)row * 2304;
  const bf16* kr = qr + 768;
  float sq = 0.f, sk = 0.f;
  if (t < 192) {
    bf16x4 q4 = ((const bf16x4*)qr)[t];
    bf16x4 k4 = ((const bf16x4*)kr)[t];
    #pragma unroll
    for (int i = 0; i < 4; ++i) {
      float qf = (float)q4[i], kf = (float)k4[i];
      sq += qf * qf; sk += kf * kf;
    }
  }
  blockReduce2(sq, sk, sm);
  if (t == 0) {
    iqn[row] = 1.0f / fmaxf(sqrtf(sq), NORM_EPS);
    ikn[row] = 1.0f / fmaxf(sqrtf(sk), NORM_EPS);
  }
}

// ---------------- 3b: kv partial sums over token chunks ----------------
// grid = 8 batches * 32 chunks, 128 tokens per chunk
__global__ __launch_bounds__(256) void kv_partial(const bf16* __restrict__ qkv,
                                                  const float* __restrict__ ikn,
                                                  float* __restrict__ kvp) {
  int b = blockIdx.x >> 5, chunk = blockIdx.x & 31;
  int t = threadIdx.x;
  const bf16* base = qkv + ((size_t)(b * 4096 + chunk * 128)) * 2304;
  const float* w = ikn + b * 4096 + chunk * 128;
  float a0 = 0.f, a1 = 0.f, a2 = 0.f;
  for (int i = 0; i < 128; ++i) {
    const bf16* kr = base + (size_t)i * 2304 + 768;
    const bf16* vr = kr + 768;
    float wi = w[i];
    a0 += (float)kr[t]       * (float)vr[t]       * wi;
    a1 += (float)kr[t + 256] * (float)vr[t + 256] * wi;
    a2 += (float)kr[t + 512] * (float)vr[t + 512] * wi;
  }
  float* o = kvp + (size_t)blockIdx.x * 768;
  o[t] = a0; o[t + 256] = a1; o[t + 512] = a2;
}

// ---------------- 3c: reduce 32 partials -> kv[8][768] ----------------
__global__ __launch_bounds__(256) void kv_reduce(const float* __restrict__ kvp,
                                                 float* __restrict__ kv) {
  int i = blockIdx.x * 256 + threadIdx.x;   // 0..6143
  int b = i / 768, e = i - b * 768;
  float s = 0.f;
  #pragma unroll
  for (int c = 0; c < 32; ++c) s += kvp[(size_t)(b * 32 + c) * 768 + e];
  kv[i] = s;
}

// ---------------- 4: attn = phi_q * kv, LayerNorm over E -> bf16 ----------------
__global__ __launch_bounds__(256) void attn_ln_kernel(const bf16* __restrict__ qkv,
                                                      const float* __restrict__ iqn,
                                                      const float* __restrict__ kv,
                                                      const float* __restrict__ g,
                                                      const float* __restrict__ b,
                                                      bf16* __restrict__ a) {
  __shared__ float sm[8];
  int row = blockIdx.x, t = threadIdx.x;
  int bt = row >> 12;
  const bf16* qr = qkv + (size_t)row * 2304;
  float iq = iqn[row];
  float4 av = make_float4(0.f, 0.f, 0.f, 0.f);
  if (t < 192) {
    bf16x4 q4 = ((const bf16x4*)qr)[t];
    float4 kv4 = ((const float4*)(kv + bt * 768))[t];
    av.x = (float)q4[0] * iq * kv4.x;
    av.y = (float)q4[1] * iq * kv4.y;
    av.z = (float)q4[2] * iq * kv4.z;
    av.w = (float)q4[3] * iq * kv4.w;
  }
  float s  = av.x + av.y + av.z + av.w;
  float ss = av.x * av.x + av.y * av.y + av.z * av.z + av.w * av.w;
  blockReduce2(s, ss, sm);
  float mu  = s * (1.0f / 768.0f);
  float inv = rsqrtf(ss * (1.0f / 768.0f) - mu * mu + LN_EPS);
  if (t < 192) {
    float4 gg = ((const float4*)g)[t];
    float4 bb = ((const float4*)b)[t];
    bf16x4 o;
    o[0] = (bf16)((av.x - mu) * inv * gg.x + bb.x);
    o[1] = (bf16)((av.y - mu) * inv * gg.y + bb.y);
    o[2] = (bf16)((av.z - mu) * inv * gg.z + bb.z);
    o[3] = (bf16)((av.w - mu) * inv * gg.w + bb.w);
    ((bf16x4*)(a + (size_t)row * 768))[t] = o;
  }
}

// ---------------- launcher ----------------
extern "C" void kernel_launch(void* const* d_in, const int* in_sizes, int n_in,
                              void* d_out, int out_size, void* d_ws, size_t ws_size,
                              hipStream_t stream) {
  const float* x      = (const float*)d_in[0];
  const float* w_qkv  = (const float*)d_in[1];
  const float* w_proj = (const float*)d_in[2];
  const float* g_in   = (const float*)d_in[3];
  const float* b_in   = (const float*)d_in[4];
  const float* g_out  = (const float*)d_in[5];
  const float* b_out  = (const float*)d_in[6];

  char* ws = (char*)d_ws;
  // workspace layout (all 16B aligned)
  bf16*  wqkvt  = (bf16*)(ws);                              // [2304][768] bf16
  bf16*  wprojt = (bf16*)(ws + 3538944);                    // [768][768]  bf16
  bf16*  h      = (bf16*)(ws + 4718592);                    // [32768][768] bf16 (reused as 'a')
  bf16*  qkv    = (bf16*)(ws + 55050240);                   // [32768][2304] bf16
  float* iqn    = (float*)(ws + 206045184);                 // [32768]
  float* ikn    = (float*)(ws + 206176256);                 // [32768]
  float* kvp    = (float*)(ws + 206307328);                 // [8*32][768]
  float* kv     = (float*)(ws + 207093760);                 // [8][768]

  transpose_cvt<<<dim3(2304 / 32, 768 / 32), 256, 0, stream>>>(w_qkv, wqkvt, 768, 2304);
  transpose_cvt<<<dim3(768 / 32, 768 / 32), 256, 0, stream>>>(w_proj, wprojt, 768, 768);
  ln_in_kernel<<<32768, 256, 0, stream>>>(x, g_in, b_in, h);
  gemm_bt<true><<<256 * 18, 256, 0, stream>>>(h, wqkvt, (void*)qkv, 2304, 18);
  norm_kernel<<<32768, 256, 0, stream>>>(qkv, iqn, ikn);
  kv_partial<<<256, 256, 0, stream>>>(qkv, ikn, kvp);
  kv_reduce<<<24, 256, 0, stream>>>(kvp, kv);
  attn_ln_kernel<<<32768, 256, 0, stream>>>(qkv, iqn, kv, g_out, b_out, h);
  gemm_bt<false><<<256 * 6, 256, 0, stream>>>(h, wprojt, d_out, 768, 6);
}

// Round 2
// 326.487 us; speedup vs baseline: 1.0139x; 1.0139x over previous
//
#include <hip/hip_runtime.h>
#include <hip/hip_bf16.h>
#include <cstdint>

typedef __bf16 bf16;
typedef __bf16 bf16x4 __attribute__((ext_vector_type(4)));
typedef __bf16 bf16x8 __attribute__((ext_vector_type(8)));
typedef float f32x4 __attribute__((ext_vector_type(4)));

#define GK 768   // inner K for both GEMMs
#define LN_EPS 1e-5f
#define NORM_EPS 1e-12f

// ---------------- async global->LDS helper ----------------
__device__ __forceinline__ void gl_lds16(const void* g, void* l) {
  __builtin_amdgcn_global_load_lds(
      (__attribute__((address_space(1))) uint32_t*)(uintptr_t)g,
      (__attribute__((address_space(3))) uint32_t*)(uintptr_t)l,
      16, 0, 0);
}

// ---------------- block reduce (2 values, 256 threads) ----------------
__device__ __forceinline__ void blockReduce2(float& s, float& ss, float* sm) {
  #pragma unroll
  for (int o = 32; o > 0; o >>= 1) {
    s  += __shfl_down(s, o, 64);
    ss += __shfl_down(ss, o, 64);
  }
  int wave = threadIdx.x >> 6, lane = threadIdx.x & 63;
  if (lane == 0) { sm[wave] = s; sm[4 + wave] = ss; }
  __syncthreads();
  s  = sm[0] + sm[1] + sm[2] + sm[3];
  ss = sm[4] + sm[5] + sm[6] + sm[7];
}

// ---------------- 0: tiled transpose + fp32->bf16 ----------------
__global__ __launch_bounds__(256) void transpose_cvt(const float* __restrict__ w,
                                                     bf16* __restrict__ wt,
                                                     int R, int Ncols) {
  __shared__ float tile[32][33];
  int tx = threadIdx.x & 31, ty = threadIdx.x >> 5;   // 32 x 8
  int c0 = blockIdx.x * 32, r0 = blockIdx.y * 32;
  #pragma unroll
  for (int i = 0; i < 32; i += 8)
    tile[ty + i][tx] = w[(size_t)(r0 + ty + i) * Ncols + (c0 + tx)];
  __syncthreads();
  #pragma unroll
  for (int i = 0; i < 32; i += 8)
    wt[(size_t)(c0 + ty + i) * R + (r0 + tx)] = (bf16)tile[tx][ty + i];
}

// ---------------- 1: input LayerNorm -> bf16 ----------------
__global__ __launch_bounds__(256) void ln_in_kernel(const float* __restrict__ x,
                                                    const float* __restrict__ g,
                                                    const float* __restrict__ b,
                                                    bf16* __restrict__ h) {
  __shared__ float sm[8];
  int row = blockIdx.x, t = threadIdx.x;
  const float* xr = x + (size_t)row * 768;
  float4 v = make_float4(0.f, 0.f, 0.f, 0.f);
  if (t < 192) v = ((const float4*)xr)[t];
  float s  = v.x + v.y + v.z + v.w;
  float ss = v.x * v.x + v.y * v.y + v.z * v.z + v.w * v.w;
  blockReduce2(s, ss, sm);
  float mu  = s * (1.0f / 768.0f);
  float inv = rsqrtf(ss * (1.0f / 768.0f) - mu * mu + LN_EPS);
  if (t < 192) {
    float4 gg = ((const float4*)g)[t];
    float4 bb = ((const float4*)b)[t];
    bf16x4 o;
    o[0] = (bf16)((v.x - mu) * inv * gg.x + bb.x);
    o[1] = (bf16)((v.y - mu) * inv * gg.y + bb.y);
    o[2] = (bf16)((v.z - mu) * inv * gg.z + bb.z);
    o[3] = (bf16)((v.w - mu) * inv * gg.w + bb.w);
    ((bf16x4*)(h + (size_t)row * 768))[t] = o;
  }
}

// ================= 256x256 8-phase bf16 GEMM (T2+T3+T4+T5) =================
// A[M][768] x Bt[N][768]^T -> C[M][N].  512 threads = 8 waves (2m x 4n).
// BK=64 -> 12 K-tiles -> 6 iterations x 2 tiles (buf0=even, buf1=odd).
// LDS 128 KiB: 2 bufs x (A 32K + B 32K). st_16x32 swizzle as involution:
// linear gl_lds dest + pre-swizzled global source + swizzled ds_read.

#define SWZ(x) ((x) ^ ((((x) >> 9) & 1) << 5))

#define PH_ENTER do { __builtin_amdgcn_sched_barrier(0); __builtin_amdgcn_s_barrier(); \
                      __builtin_amdgcn_sched_barrier(0); } while (0)
#define PH_EXIT  do { __builtin_amdgcn_sched_barrier(0); __builtin_amdgcn_s_barrier(); \
                      __builtin_amdgcn_sched_barrier(0); } while (0)
#define PH_EXIT_V do { __builtin_amdgcn_sched_barrier(0); \
                       asm volatile("s_waitcnt vmcnt(4)" ::: "memory"); \
                       __builtin_amdgcn_s_barrier(); \
                       __builtin_amdgcn_sched_barrier(0); } while (0)

#define LDA1(base, mh, i, ks) \
  af[i][ks] = *(const bf16x8*)((base) + SWZ((wm * 128 + ((mh) * 4 + (i)) * 16 + llo) * 128 + (ks) * 64 + lhi * 16))
#define LDAQ(base, mh) do { \
  LDA1(base, mh, 0, 0); LDA1(base, mh, 0, 1); LDA1(base, mh, 1, 0); LDA1(base, mh, 1, 1); \
  LDA1(base, mh, 2, 0); LDA1(base, mh, 2, 1); LDA1(base, mh, 3, 0); LDA1(base, mh, 3, 1); } while (0)

#define LDB1(base, n, ks) \
  bf[n][ks] = *(const bf16x8*)((base) + SWZ(((((n) >> 1) * 128 + wn * 32 + ((n) & 1) * 16 + llo) * 128 + (ks) * 64 + lhi * 16)))
#define LDBH(base, nlo) do { \
  LDB1(base, nlo, 0); LDB1(base, nlo, 1); LDB1(base, (nlo) + 1, 0); LDB1(base, (nlo) + 1, 1); } while (0)

#define MF1(mh, nh, i, jn, ks) \
  acc[(mh) * 4 + (i)][(nh) * 2 + (jn)] = __builtin_amdgcn_mfma_f32_16x16x32_bf16( \
      af[i][ks], bf[(nh) * 2 + (jn)][ks], acc[(mh) * 4 + (i)][(nh) * 2 + (jn)], 0, 0, 0)
#define MFQ(mh, nh) do { \
  __builtin_amdgcn_s_setprio(1); \
  MF1(mh, nh, 0, 0, 0); MF1(mh, nh, 0, 1, 0); MF1(mh, nh, 1, 0, 0); MF1(mh, nh, 1, 1, 0); \
  MF1(mh, nh, 2, 0, 0); MF1(mh, nh, 2, 1, 0); MF1(mh, nh, 3, 0, 0); MF1(mh, nh, 3, 1, 0); \
  MF1(mh, nh, 0, 0, 1); MF1(mh, nh, 0, 1, 1); MF1(mh, nh, 1, 0, 1); MF1(mh, nh, 1, 1, 1); \
  MF1(mh, nh, 2, 0, 1); MF1(mh, nh, 2, 1, 1); MF1(mh, nh, 3, 0, 1); MF1(mh, nh, 3, 1, 1); \
  __builtin_amdgcn_s_setprio(0); } while (0)

#define STA(b, q, kt) gl_lds16(A + srcA[q] + (kt) * 64, &As_[b][(q) * 4096 + wave * 512])
#define STB(b, q, kt) gl_lds16(Bt + srcB[q] + (kt) * 64, &Bs_[b][(q) * 4096 + wave * 512])

template <bool OUT_BF16>
__global__ __launch_bounds__(512, 2) void gemm8p(const bf16* __restrict__ A,
                                                 const bf16* __restrict__ Bt,
                                                 void* __restrict__ Cv,
                                                 int Nn, int NBN) {
  __shared__ __align__(16) bf16 As_[2][16384];
  __shared__ __align__(16) bf16 Bs_[2][16384];
  const int tid = threadIdx.x;
  const int wave = tid >> 6, lane = tid & 63;
  const int llo = lane & 15, lhi = lane >> 4;
  const int wm = wave >> 2, wn = wave & 3;

  const int nwg = gridDim.x, bid = blockIdx.x;
  const int wg = (bid & 7) * (nwg >> 3) + (bid >> 3);
  const int rb = wg / NBN, cb = wg - rb * NBN;
  const int brow = rb * 256, bcol = cb * 256;

  // stage source element-offsets per chunk slot (involution pre-swizzle)
  uint32_t srcA[4], srcB[4];
  #pragma unroll
  for (int q = 0; q < 4; ++q) {
    int d = q * 8192 + tid * 16;          // dest byte offset within 32KB tile
    int a = SWZ(d);                       // logical byte offset
    int r = a >> 7, c = (a & 127) >> 1;   // logical row / bf16 col
    srcA[q] = (uint32_t)(brow + r) * GK + c;
    int nh = r >> 7, wnn = (r >> 5) & 3, r32 = r & 31;  // B row permutation
    srcB[q] = (uint32_t)(bcol + wnn * 64 + nh * 32 + r32) * GK + c;
  }

  f32x4 acc[8][4];
  #pragma unroll
  for (int m = 0; m < 8; ++m)
    #pragma unroll
    for (int n = 0; n < 4; ++n) acc[m][n] = (f32x4){0.f, 0.f, 0.f, 0.f};

  bf16x8 af[4][2], bf[4][2];
  const char* As0 = (const char*)&As_[0][0];
  const char* As1 = (const char*)&As_[1][0];
  const char* Bs0 = (const char*)&Bs_[0][0];
  const char* Bs1 = (const char*)&Bs_[1][0];

  // -------- prologue: tile0 full (8), tile1 partial (4); keep 4 in flight
  STA(0, 0, 0); STA(0, 1, 0); STA(0, 2, 0); STA(0, 3, 0);
  STB(0, 0, 0); STB(0, 1, 0); STB(0, 2, 0); STB(0, 3, 0);
  STA(1, 0, 1); STA(1, 2, 1); STB(1, 0, 1); STB(1, 1, 1);
  __builtin_amdgcn_sched_barrier(0);
  asm volatile("s_waitcnt vmcnt(4)" ::: "memory");
  __builtin_amdgcn_s_barrier();
  __builtin_amdgcn_sched_barrier(0);

  for (int j = 0; j < 6; ++j) {
    const int t1 = 2 * j + 1, t2 = 2 * j + 2, t3 = 2 * j + 3;
    // ph1: compute (m0,n01) of even tile; finish odd tile's A
    LDAQ(As0, 0); LDBH(Bs0, 0);
    STA(1, 1, t1); STA(1, 3, t1);
    PH_ENTER; MFQ(0, 0); PH_EXIT;
    // ph2: finish odd tile's B-h1
    LDBH(Bs0, 2);
    STB(1, 2, t1); STB(1, 3, t1);
    PH_ENTER; MFQ(0, 1); PH_EXIT;
    // ph3: next even tile A q0,q2
    LDAQ(As0, 1);
    STA(0, 0, t2); STA(0, 2, t2);
    PH_ENTER; MFQ(1, 0); PH_EXIT;
    // ph4: next even tile B h0 ; counted wait for odd-tile data
    STB(0, 0, t2); STB(0, 1, t2);
    PH_ENTER; MFQ(1, 1); PH_EXIT_V;
    // ph5..8: odd tile from buf1
    LDAQ(As1, 0); LDBH(Bs1, 0);
    STA(0, 1, t2); STA(0, 3, t2);
    PH_ENTER; MFQ(0, 0); PH_EXIT;
    LDBH(Bs1, 2);
    STB(0, 2, t2); STB(0, 3, t2);
    PH_ENTER; MFQ(0, 1); PH_EXIT;
    LDAQ(As1, 1);
    STA(1, 0, t3); STA(1, 2, t3);
    PH_ENTER; MFQ(1, 0); PH_EXIT;
    STB(1, 0, t3); STB(1, 1, t3);
    PH_ENTER; MFQ(1, 1); PH_EXIT_V;
  }

  // -------- epilogue: C write
  #pragma unroll
  for (int m = 0; m < 8; ++m) {
    #pragma unroll
    for (int n = 0; n < 4; ++n) {
      int row = brow + wm * 128 + m * 16 + lhi * 4;
      int col = bcol + wn * 64 + n * 16 + llo;
      #pragma unroll
      for (int r2 = 0; r2 < 4; ++r2) {
        if (OUT_BF16)
          ((bf16*)Cv)[(size_t)(row + r2) * Nn + col] = (bf16)acc[m][n][r2];
        else
          ((float*)Cv)[(size_t)(row + r2) * Nn + col] = acc[m][n][r2];
      }
    }
  }
}

// ---------------- 3a: per-token inverse L2 norms of q and k ----------------
__global__ __launch_bounds__(256) void norm_kernel(const bf16* __restrict__ qkv,
                                                   float* __restrict__ iqn,
                                                   float* __restrict__ ikn) {
  __shared__ float sm[8];
  int row = blockIdx.x, t = threadIdx.x;
  const bf16* qr = qkv + (size_t)row * 2304;
  const bf16* kr = qr + 768;
  float sq = 0.f, sk = 0.f;
  if (t < 192) {
    bf16x4 q4 = ((const bf16x4*)qr)[t];
    bf16x4 k4 = ((const bf16x4*)kr)[t];
    #pragma unroll
    for (int i = 0; i < 4; ++i) {
      float qf = (float)q4[i], kf = (float)k4[i];
      sq += qf * qf; sk += kf * kf;
    }
  }
  blockReduce2(sq, sk, sm);
  if (t == 0) {
    iqn[row] = 1.0f / fmaxf(sqrtf(sq), NORM_EPS);
    ikn[row] = 1.0f / fmaxf(sqrtf(sk), NORM_EPS);
  }
}

// ---------------- 3b: kv partial sums over token chunks ----------------
__global__ __launch_bounds__(256) void kv_partial(const bf16* __restrict__ qkv,
                                                  const float* __restrict__ ikn,
                                                  float* __restrict__ kvp) {
  int b = blockIdx.x >> 5, chunk = blockIdx.x & 31;
  int t = threadIdx.x;
  const bf16* base = qkv + ((size_t)(b * 4096 + chunk * 128)) * 2304;
  const float* w = ikn + b * 4096 + chunk * 128;
  float a0 = 0.f, a1 = 0.f, a2 = 0.f;
  for (int i = 0; i < 128; ++i) {
    const bf16* kr = base + (size_t)i * 2304 + 768;
    const bf16* vr = kr + 768;
    float wi = w[i];
    a0 += (float)kr[t]       * (float)vr[t]       * wi;
    a1 += (float)kr[t + 256] * (float)vr[t + 256] * wi;
    a2 += (float)kr[t + 512] * (float)vr[t + 512] * wi;
  }
  float* o = kvp + (size_t)blockIdx.x * 768;
  o[t] = a0; o[t + 256] = a1; o[t + 512] = a2;
}

// ---------------- 3c: reduce 32 partials -> kv[8][768] ----------------
__global__ __launch_bounds__(256) void kv_reduce(const float* __restrict__ kvp,
                                                 float* __restrict__ kv) {
  int i = blockIdx.x * 256 + threadIdx.x;   // 0..6143
  int b = i / 768, e = i - b * 768;
  float s = 0.f;
  #pragma unroll
  for (int c = 0; c < 32; ++c) s += kvp[(size_t)(b * 32 + c) * 768 + e];
  kv[i] = s;
}

// ---------------- 4: attn = phi_q * kv, LayerNorm over E -> bf16 ----------------
__global__ __launch_bounds__(256) void attn_ln_kernel(const bf16* __restrict__ qkv,
                                                      const float* __restrict__ iqn,
                                                      const float* __restrict__ kv,
                                                      const float* __restrict__ g,
                                                      const float* __restrict__ b,
                                                      bf16* __restrict__ a) {
  __shared__ float sm[8];
  int row = blockIdx.x, t = threadIdx.x;
  int bt = row >> 12;
  const bf16* qr = qkv + (size_t)row * 2304;
  float iq = iqn[row];
  float4 av = make_float4(0.f, 0.f, 0.f, 0.f);
  if (t < 192) {
    bf16x4 q4 = ((const bf16x4*)qr)[t];
    float4 kv4 = ((const float4*)(kv + bt * 768))[t];
    av.x = (float)q4[0] * iq * kv4.x;
    av.y = (float)q4[1] * iq * kv4.y;
    av.z = (float)q4[2] * iq * kv4.z;
    av.w = (float)q4[3] * iq * kv4.w;
  }
  float s  = av.x + av.y + av.z + av.w;
  float ss = av.x * av.x + av.y * av.y + av.z * av.z + av.w * av.w;
  blockReduce2(s, ss, sm);
  float mu  = s * (1.0f / 768.0f);
  float inv = rsqrtf(ss * (1.0f / 768.0f) - mu * mu + LN_EPS);
  if (t < 192) {
    float4 gg = ((const float4*)g)[t];
    float4 bb = ((const float4*)b)[t];
    bf16x4 o;
    o[0] = (bf16)((av.x - mu) * inv * gg.x + bb.x);
    o[1] = (bf16)((av.y - mu) * inv * gg.y + bb.y);
    o[2] = (bf16)((av.z - mu) * inv * gg.z + bb.z);
    o[3] = (bf16)((av.w - mu) * inv * gg.w + bb.w);
    ((bf16x4*)(a + (size_t)row * 768))[t] = o;
  }
}

// ---------------- launcher ----------------
extern "C" void kernel_launch(void* const* d_in, const int* in_sizes, int n_in,
                              void* d_out, int out_size, void* d_ws, size_t ws_size,
                              hipStream_t stream) {
  const float* x      = (const float*)d_in[0];
  const float* w_qkv  = (const float*)d_in[1];
  const float* w_proj = (const float*)d_in[2];
  const float* g_in   = (const float*)d_in[3];
  const float* b_in   = (const float*)d_in[4];
  const float* g_out  = (const float*)d_in[5];
  const float* b_out  = (const float*)d_in[6];

  char* ws = (char*)d_ws;
  bf16*  wqkvt  = (bf16*)(ws);                              // [2304][768] bf16
  bf16*  wprojt = (bf16*)(ws + 3538944);                    // [768][768]  bf16
  bf16*  h      = (bf16*)(ws + 4718592);                    // [32768][768] bf16 (reused as 'a')
  bf16*  qkv    = (bf16*)(ws + 55050240);                   // [32768][2304] bf16
  float* iqn    = (float*)(ws + 206045184);                 // [32768]
  float* ikn    = (float*)(ws + 206176256);                 // [32768]
  float* kvp    = (float*)(ws + 206307328);                 // [8*32][768]
  float* kv     = (float*)(ws + 207093760);                 // [8][768]

  transpose_cvt<<<dim3(2304 / 32, 768 / 32), 256, 0, stream>>>(w_qkv, wqkvt, 768, 2304);
  transpose_cvt<<<dim3(768 / 32, 768 / 32), 256, 0, stream>>>(w_proj, wprojt, 768, 768);
  ln_in_kernel<<<32768, 256, 0, stream>>>(x, g_in, b_in, h);
  gemm8p<true><<<128 * 9, 512, 0, stream>>>(h, wqkvt, (void*)qkv, 2304, 9);
  norm_kernel<<<32768, 256, 0, stream>>>(qkv, iqn, ikn);
  kv_partial<<<256, 256, 0, stream>>>(qkv, ikn, kvp);
  kv_reduce<<<24, 256, 0, stream>>>(kvp, kv);
  attn_ln_kernel<<<32768, 256, 0, stream>>>(qkv, iqn, kv, g_out, b_out, h);
  gemm8p<false><<<128 * 3, 512, 0, stream>>>(h, wprojt, d_out, 768, 3);
}

// Round 3
// 298.510 us; speedup vs baseline: 1.1090x; 1.0937x over previous
//
#include <hip/hip_runtime.h>
#include <hip/hip_bf16.h>
#include <cstdint>

typedef __bf16 bf16;
typedef __bf16 bf16x4 __attribute__((ext_vector_type(4)));
typedef __bf16 bf16x8 __attribute__((ext_vector_type(8)));
typedef float f32x4 __attribute__((ext_vector_type(4)));

#define GK 768   // inner K for both GEMMs
#define LN_EPS 1e-5f
#define NORM_EPS 1e-12f

// ---------------- async global->LDS helper ----------------
__device__ __forceinline__ void gl_lds16(const void* g, void* l) {
  __builtin_amdgcn_global_load_lds(
      (__attribute__((address_space(1))) uint32_t*)(uintptr_t)g,
      (__attribute__((address_space(3))) uint32_t*)(uintptr_t)l,
      16, 0, 0);
}

// ---------------- block reduce (2 values, 256 threads) ----------------
__device__ __forceinline__ void blockReduce2(float& s, float& ss, float* sm) {
  #pragma unroll
  for (int o = 32; o > 0; o >>= 1) {
    s  += __shfl_down(s, o, 64);
    ss += __shfl_down(ss, o, 64);
  }
  int wave = threadIdx.x >> 6, lane = threadIdx.x & 63;
  if (lane == 0) { sm[wave] = s; sm[4 + wave] = ss; }
  __syncthreads();
  s  = sm[0] + sm[1] + sm[2] + sm[3];
  ss = sm[4] + sm[5] + sm[6] + sm[7];
  __syncthreads();   // allow immediate reuse of sm
}

// ---------------- 0: tiled transpose + fp32->bf16 ----------------
__global__ __launch_bounds__(256) void transpose_cvt(const float* __restrict__ w,
                                                     bf16* __restrict__ wt,
                                                     int R, int Ncols) {
  __shared__ float tile[32][33];
  int tx = threadIdx.x & 31, ty = threadIdx.x >> 5;   // 32 x 8
  int c0 = blockIdx.x * 32, r0 = blockIdx.y * 32;
  #pragma unroll
  for (int i = 0; i < 32; i += 8)
    tile[ty + i][tx] = w[(size_t)(r0 + ty + i) * Ncols + (c0 + tx)];
  __syncthreads();
  #pragma unroll
  for (int i = 0; i < 32; i += 8)
    wt[(size_t)(c0 + ty + i) * R + (r0 + tx)] = (bf16)tile[tx][ty + i];
}

// ---------------- 1: input LayerNorm -> bf16 ----------------
__global__ __launch_bounds__(256) void ln_in_kernel(const float* __restrict__ x,
                                                    const float* __restrict__ g,
                                                    const float* __restrict__ b,
                                                    bf16* __restrict__ h) {
  __shared__ float sm[8];
  int row = blockIdx.x, t = threadIdx.x;
  const float* xr = x + (size_t)row * 768;
  float4 v = make_float4(0.f, 0.f, 0.f, 0.f);
  if (t < 192) v = ((const float4*)xr)[t];
  float s  = v.x + v.y + v.z + v.w;
  float ss = v.x * v.x + v.y * v.y + v.z * v.z + v.w * v.w;
  blockReduce2(s, ss, sm);
  float mu  = s * (1.0f / 768.0f);
  float inv = rsqrtf(ss * (1.0f / 768.0f) - mu * mu + LN_EPS);
  if (t < 192) {
    float4 gg = ((const float4*)g)[t];
    float4 bb = ((const float4*)b)[t];
    bf16x4 o;
    o[0] = (bf16)((v.x - mu) * inv * gg.x + bb.x);
    o[1] = (bf16)((v.y - mu) * inv * gg.y + bb.y);
    o[2] = (bf16)((v.z - mu) * inv * gg.z + bb.z);
    o[3] = (bf16)((v.w - mu) * inv * gg.w + bb.w);
    ((bf16x4*)(h + (size_t)row * 768))[t] = o;
  }
}

// ================= 256x256 8-phase bf16 GEMM (T2+T3+T4+T5) =================
// A[M][768] x Bt[N][768]^T -> C[M][N].  512 threads = 8 waves (2m x 4n).
// BK=64 -> 12 K-tiles -> 6 iterations x 2 tiles (buf0=even, buf1=odd).
// LDS 128 KiB: 2 bufs x (A 32K + B 32K).
// T2 swizzle: XOR byte-bits 4-6 with row-bits 0-2 (involution on 16B slots);
// linear gl_lds dest + pre-swizzled global source + swizzled ds_read.

#define SWZ(x) ((x) ^ ((((x) >> 7) & 7) << 4))

#define PH_ENTER do { __builtin_amdgcn_sched_barrier(0); __builtin_amdgcn_s_barrier(); \
                      __builtin_amdgcn_sched_barrier(0); } while (0)
#define PH_EXIT  do { __builtin_amdgcn_sched_barrier(0); __builtin_amdgcn_s_barrier(); \
                      __builtin_amdgcn_sched_barrier(0); } while (0)
#define PH_EXIT_V do { __builtin_amdgcn_sched_barrier(0); \
                       asm volatile("s_waitcnt vmcnt(4)" ::: "memory"); \
                       __builtin_amdgcn_s_barrier(); \
                       __builtin_amdgcn_sched_barrier(0); } while (0)

#define LDA1(base, mh, i, ks) \
  af[i][ks] = *(const bf16x8*)((base) + SWZ((wm * 128 + ((mh) * 4 + (i)) * 16 + llo) * 128 + (ks) * 64 + lhi * 16))
#define LDAQ(base, mh) do { \
  LDA1(base, mh, 0, 0); LDA1(base, mh, 0, 1); LDA1(base, mh, 1, 0); LDA1(base, mh, 1, 1); \
  LDA1(base, mh, 2, 0); LDA1(base, mh, 2, 1); LDA1(base, mh, 3, 0); LDA1(base, mh, 3, 1); } while (0)

#define LDB1(base, n, ks) \
  bf[n][ks] = *(const bf16x8*)((base) + SWZ(((((n) >> 1) * 128 + wn * 32 + ((n) & 1) * 16 + llo) * 128 + (ks) * 64 + lhi * 16)))
#define LDBH(base, nlo) do { \
  LDB1(base, nlo, 0); LDB1(base, nlo, 1); LDB1(base, (nlo) + 1, 0); LDB1(base, (nlo) + 1, 1); } while (0)

#define MF1(mh, nh, i, jn, ks) \
  acc[(mh) * 4 + (i)][(nh) * 2 + (jn)] = __builtin_amdgcn_mfma_f32_16x16x32_bf16( \
      af[i][ks], bf[(nh) * 2 + (jn)][ks], acc[(mh) * 4 + (i)][(nh) * 2 + (jn)], 0, 0, 0)
#define MFQ(mh, nh) do { \
  __builtin_amdgcn_s_setprio(1); \
  MF1(mh, nh, 0, 0, 0); MF1(mh, nh, 0, 1, 0); MF1(mh, nh, 1, 0, 0); MF1(mh, nh, 1, 1, 0); \
  MF1(mh, nh, 2, 0, 0); MF1(mh, nh, 2, 1, 0); MF1(mh, nh, 3, 0, 0); MF1(mh, nh, 3, 1, 0); \
  MF1(mh, nh, 0, 0, 1); MF1(mh, nh, 0, 1, 1); MF1(mh, nh, 1, 0, 1); MF1(mh, nh, 1, 1, 1); \
  MF1(mh, nh, 2, 0, 1); MF1(mh, nh, 2, 1, 1); MF1(mh, nh, 3, 0, 1); MF1(mh, nh, 3, 1, 1); \
  __builtin_amdgcn_s_setprio(0); } while (0)

#define STA(b, q, kt) gl_lds16(A + srcA[q] + (kt) * 64, &As_[b][(q) * 4096 + wave * 512])
#define STB(b, q, kt) gl_lds16(Bt + srcB[q] + (kt) * 64, &Bs_[b][(q) * 4096 + wave * 512])

template <bool OUT_BF16>
__global__ __launch_bounds__(512, 2) void gemm8p(const bf16* __restrict__ A,
                                                 const bf16* __restrict__ Bt,
                                                 void* __restrict__ Cv,
                                                 int Nn, int NBN) {
  __shared__ __align__(16) bf16 As_[2][16384];
  __shared__ __align__(16) bf16 Bs_[2][16384];
  const int tid = threadIdx.x;
  const int wave = tid >> 6, lane = tid & 63;
  const int llo = lane & 15, lhi = lane >> 4;
  const int wm = wave >> 2, wn = wave & 3;

  const int nwg = gridDim.x, bid = blockIdx.x;
  const int wg = (bid & 7) * (nwg >> 3) + (bid >> 3);
  const int rb = wg / NBN, cb = wg - rb * NBN;
  const int brow = rb * 256, bcol = cb * 256;

  // stage source element-offsets per chunk slot (involution pre-swizzle)
  uint32_t srcA[4], srcB[4];
  #pragma unroll
  for (int q = 0; q < 4; ++q) {
    int d = q * 8192 + tid * 16;          // dest byte offset within 32KB tile
    int a = SWZ(d);                       // logical byte offset
    int r = a >> 7, c = (a & 127) >> 1;   // logical row / bf16 col
    srcA[q] = (uint32_t)(brow + r) * GK + c;
    int nh = r >> 7, wnn = (r >> 5) & 3, r32 = r & 31;  // B row permutation
    srcB[q] = (uint32_t)(bcol + wnn * 64 + nh * 32 + r32) * GK + c;
  }

  f32x4 acc[8][4];
  #pragma unroll
  for (int m = 0; m < 8; ++m)
    #pragma unroll
    for (int n = 0; n < 4; ++n) acc[m][n] = (f32x4){0.f, 0.f, 0.f, 0.f};

  bf16x8 af[4][2], bf[4][2];
  const char* As0 = (const char*)&As_[0][0];
  const char* As1 = (const char*)&As_[1][0];
  const char* Bs0 = (const char*)&Bs_[0][0];
  const char* Bs1 = (const char*)&Bs_[1][0];

  // -------- prologue: tile0 full (8), tile1 partial (4); keep 4 in flight
  STA(0, 0, 0); STA(0, 1, 0); STA(0, 2, 0); STA(0, 3, 0);
  STB(0, 0, 0); STB(0, 1, 0); STB(0, 2, 0); STB(0, 3, 0);
  STA(1, 0, 1); STA(1, 2, 1); STB(1, 0, 1); STB(1, 1, 1);
  __builtin_amdgcn_sched_barrier(0);
  asm volatile("s_waitcnt vmcnt(4)" ::: "memory");
  __builtin_amdgcn_s_barrier();
  __builtin_amdgcn_sched_barrier(0);

  for (int j = 0; j < 6; ++j) {
    const int t1 = 2 * j + 1, t2 = 2 * j + 2, t3 = 2 * j + 3;
    // ph1: compute (m0,n01) of even tile; finish odd tile's A
    LDAQ(As0, 0); LDBH(Bs0, 0);
    STA(1, 1, t1); STA(1, 3, t1);
    PH_ENTER; MFQ(0, 0); PH_EXIT;
    // ph2: finish odd tile's B-h1
    LDBH(Bs0, 2);
    STB(1, 2, t1); STB(1, 3, t1);
    PH_ENTER; MFQ(0, 1); PH_EXIT;
    // ph3: next even tile A q0,q2
    LDAQ(As0, 1);
    STA(0, 0, t2); STA(0, 2, t2);
    PH_ENTER; MFQ(1, 0); PH_EXIT;
    // ph4: next even tile B h0 ; counted wait for odd-tile data
    STB(0, 0, t2); STB(0, 1, t2);
    PH_ENTER; MFQ(1, 1); PH_EXIT_V;
    // ph5..8: odd tile from buf1
    LDAQ(As1, 0); LDBH(Bs1, 0);
    STA(0, 1, t2); STA(0, 3, t2);
    PH_ENTER; MFQ(0, 0); PH_EXIT;
    LDBH(Bs1, 2);
    STB(0, 2, t2); STB(0, 3, t2);
    PH_ENTER; MFQ(0, 1); PH_EXIT;
    LDAQ(As1, 1);
    STA(1, 0, t3); STA(1, 2, t3);
    PH_ENTER; MFQ(1, 0); PH_EXIT;
    STB(1, 0, t3); STB(1, 1, t3);
    PH_ENTER; MFQ(1, 1); PH_EXIT_V;
  }

  // -------- epilogue: C write
  #pragma unroll
  for (int m = 0; m < 8; ++m) {
    #pragma unroll
    for (int n = 0; n < 4; ++n) {
      int row = brow + wm * 128 + m * 16 + lhi * 4;
      int col = bcol + wn * 64 + n * 16 + llo;
      #pragma unroll
      for (int r2 = 0; r2 < 4; ++r2) {
        if (OUT_BF16)
          ((bf16*)Cv)[(size_t)(row + r2) * Nn + col] = (bf16)acc[m][n][r2];
        else
          ((float*)Cv)[(size_t)(row + r2) * Nn + col] = acc[m][n][r2];
      }
    }
  }
}

// ---------------- 3a: kv partial sums, k-norm computed inline ----------------
// grid = 8 batches * 32 chunks of 128 tokens; wave w owns 32 tokens.
__global__ __launch_bounds__(256) void kv_partial(const bf16* __restrict__ qkv,
                                                  float* __restrict__ kvp) {
  __shared__ float sm[4][768];
  int b = blockIdx.x >> 5, chunk = blockIdx.x & 31;
  int wave = threadIdx.x >> 6, lane = threadIdx.x & 63;
  const bf16* base = qkv + ((size_t)(b * 4096 + chunk * 128 + wave * 32)) * 2304;
  float acc[3][4] = {};
  for (int i = 0; i < 32; ++i) {
    const bf16* kr = base + (size_t)i * 2304 + 768;
    const bf16* vr = kr + 768;
    bf16x4 k4[3], v4[3];
    #pragma unroll
    for (int c = 0; c < 3; ++c) {
      k4[c] = *(const bf16x4*)(kr + c * 256 + lane * 4);
      v4[c] = *(const bf16x4*)(vr + c * 256 + lane * 4);
    }
    float ssk = 0.f;
    #pragma unroll
    for (int c = 0; c < 3; ++c)
      #pragma unroll
      for (int j = 0; j < 4; ++j) { float kf = (float)k4[c][j]; ssk += kf * kf; }
    #pragma unroll
    for (int off = 32; off > 0; off >>= 1) ssk += __shfl_xor(ssk, off, 64);
    float wi = 1.0f / fmaxf(sqrtf(ssk), NORM_EPS);
    #pragma unroll
    for (int c = 0; c < 3; ++c)
      #pragma unroll
      for (int j = 0; j < 4; ++j)
        acc[c][j] += (float)k4[c][j] * (float)v4[c][j] * wi;
  }
  #pragma unroll
  for (int c = 0; c < 3; ++c)
    #pragma unroll
    for (int j = 0; j < 4; ++j)
      sm[wave][c * 256 + lane * 4 + j] = acc[c][j];
  __syncthreads();
  int t = threadIdx.x;
  #pragma unroll
  for (int c = 0; c < 3; ++c) {
    int e = c * 256 + t;
    kvp[(size_t)blockIdx.x * 768 + e] = sm[0][e] + sm[1][e] + sm[2][e] + sm[3][e];
  }
}

// ---------------- 3b: reduce 32 partials -> kv[8][768] ----------------
__global__ __launch_bounds__(256) void kv_reduce(const float* __restrict__ kvp,
                                                 float* __restrict__ kv) {
  int i = blockIdx.x * 256 + threadIdx.x;   // 0..6143
  int b = i / 768, e = i - b * 768;
  float s = 0.f;
  #pragma unroll
  for (int c = 0; c < 32; ++c) s += kvp[(size_t)(b * 32 + c) * 768 + e];
  kv[i] = s;
}

// ---------------- 4: attn = phi_q * kv (q-norm inline), LN over E -> bf16 ----
__global__ __launch_bounds__(256) void attn_ln_kernel(const bf16* __restrict__ qkv,
                                                      const float* __restrict__ kv,
                                                      const float* __restrict__ g,
                                                      const float* __restrict__ b,
                                                      bf16* __restrict__ a) {
  __shared__ float sm[8];
  int row = blockIdx.x, t = threadIdx.x;
  int bt = row >> 12;
  const bf16* qr = qkv + (size_t)row * 2304;
  bf16x4 q4 = {};
  if (t < 192) q4 = ((const bf16x4*)qr)[t];
  float q0 = (float)q4[0], q1 = (float)q4[1], q2 = (float)q4[2], q3 = (float)q4[3];
  float sq = q0 * q0 + q1 * q1 + q2 * q2 + q3 * q3, dummy = 0.f;
  blockReduce2(sq, dummy, sm);
  float iq = 1.0f / fmaxf(sqrtf(sq), NORM_EPS);
  float4 av = make_float4(0.f, 0.f, 0.f, 0.f);
  if (t < 192) {
    float4 kv4 = ((const float4*)(kv + bt * 768))[t];
    av.x = q0 * iq * kv4.x;
    av.y = q1 * iq * kv4.y;
    av.z = q2 * iq * kv4.z;
    av.w = q3 * iq * kv4.w;
  }
  float s  = av.x + av.y + av.z + av.w;
  float ss = av.x * av.x + av.y * av.y + av.z * av.z + av.w * av.w;
  blockReduce2(s, ss, sm);
  float mu  = s * (1.0f / 768.0f);
  float inv = rsqrtf(ss * (1.0f / 768.0f) - mu * mu + LN_EPS);
  if (t < 192) {
    float4 gg = ((const float4*)g)[t];
    float4 bb = ((const float4*)b)[t];
    bf16x4 o;
    o[0] = (bf16)((av.x - mu) * inv * gg.x + bb.x);
    o[1] = (bf16)((av.y - mu) * inv * gg.y + bb.y);
    o[2] = (bf16)((av.z - mu) * inv * gg.z + bb.z);
    o[3] = (bf16)((av.w - mu) * inv * gg.w + bb.w);
    ((bf16x4*)(a + (size_t)row * 768))[t] = o;
  }
}

// ---------------- launcher ----------------
extern "C" void kernel_launch(void* const* d_in, const int* in_sizes, int n_in,
                              void* d_out, int out_size, void* d_ws, size_t ws_size,
                              hipStream_t stream) {
  const float* x      = (const float*)d_in[0];
  const float* w_qkv  = (const float*)d_in[1];
  const float* w_proj = (const float*)d_in[2];
  const float* g_in   = (const float*)d_in[3];
  const float* b_in   = (const float*)d_in[4];
  const float* g_out  = (const float*)d_in[5];
  const float* b_out  = (const float*)d_in[6];

  char* ws = (char*)d_ws;
  bf16*  wqkvt  = (bf16*)(ws);                              // [2304][768] bf16
  bf16*  wprojt = (bf16*)(ws + 3538944);                    // [768][768]  bf16
  bf16*  h      = (bf16*)(ws + 4718592);                    // [32768][768] bf16 (reused as 'a')
  bf16*  qkv    = (bf16*)(ws + 55050240);                   // [32768][2304] bf16
  float* kvp    = (float*)(ws + 206045184);                 // [8*32][768]
  float* kv     = (float*)(ws + 206831616);                 // [8][768]

  transpose_cvt<<<dim3(2304 / 32, 768 / 32), 256, 0, stream>>>(w_qkv, wqkvt, 768, 2304);
  transpose_cvt<<<dim3(768 / 32, 768 / 32), 256, 0, stream>>>(w_proj, wprojt, 768, 768);
  ln_in_kernel<<<32768, 256, 0, stream>>>(x, g_in, b_in, h);
  gemm8p<true><<<128 * 9, 512, 0, stream>>>(h, wqkvt, (void*)qkv, 2304, 9);
  kv_partial<<<256, 256, 0, stream>>>(qkv, kvp);
  kv_reduce<<<24, 256, 0, stream>>>(kvp, kv);
  attn_ln_kernel<<<32768, 256, 0, stream>>>(qkv, kv, g_out, b_out, h);
  gemm8p<false><<<128 * 3, 512, 0, stream>>>(h, wprojt, d_out, 768, 3);
}

// Round 4
// 292.642 us; speedup vs baseline: 1.1312x; 1.0201x over previous
//
#include <hip/hip_runtime.h>
#include <hip/hip_bf16.h>
#include <cstdint>

typedef __bf16 bf16;
typedef __bf16 bf16x4 __attribute__((ext_vector_type(4)));
typedef __bf16 bf16x8 __attribute__((ext_vector_type(8)));
typedef float f32x4 __attribute__((ext_vector_type(4)));

#define GK 768   // inner K for both GEMMs
#define LN_EPS 1e-5f
#define NORM_EPS 1e-12f

// ---------------- async global->LDS helper ----------------
__device__ __forceinline__ void gl_lds16(const void* g, void* l) {
  __builtin_amdgcn_global_load_lds(
      (__attribute__((address_space(1))) uint32_t*)(uintptr_t)g,
      (__attribute__((address_space(3))) uint32_t*)(uintptr_t)l,
      16, 0, 0);
}

// ---------------- block reduce (2 values, 3 waves / 192 threads) ----------------
__device__ __forceinline__ void blockReduce2w3(float& s, float& ss, float* sm) {
  #pragma unroll
  for (int o = 32; o > 0; o >>= 1) {
    s  += __shfl_down(s, o, 64);
    ss += __shfl_down(ss, o, 64);
  }
  int wave = threadIdx.x >> 6, lane = threadIdx.x & 63;
  if (lane == 0) { sm[wave] = s; sm[3 + wave] = ss; }
  __syncthreads();
  s  = sm[0] + sm[1] + sm[2];
  ss = sm[3] + sm[4] + sm[5];
  __syncthreads();   // allow immediate reuse of sm
}

// ---------------- 0: tiled transpose + fp32->bf16 ----------------
__global__ __launch_bounds__(256) void transpose_cvt(const float* __restrict__ w,
                                                     bf16* __restrict__ wt,
                                                     int R, int Ncols) {
  __shared__ float tile[32][33];
  int tx = threadIdx.x & 31, ty = threadIdx.x >> 5;   // 32 x 8
  int c0 = blockIdx.x * 32, r0 = blockIdx.y * 32;
  #pragma unroll
  for (int i = 0; i < 32; i += 8)
    tile[ty + i][tx] = w[(size_t)(r0 + ty + i) * Ncols + (c0 + tx)];
  __syncthreads();
  #pragma unroll
  for (int i = 0; i < 32; i += 8)
    wt[(size_t)(c0 + ty + i) * R + (r0 + tx)] = (bf16)tile[tx][ty + i];
}

// ---------------- 1: input LayerNorm -> bf16 (192 threads = 3 waves) ----------
__global__ __launch_bounds__(192) void ln_in_kernel(const float* __restrict__ x,
                                                    const float* __restrict__ g,
                                                    const float* __restrict__ b,
                                                    bf16* __restrict__ h) {
  __shared__ float sm[6];
  int row = blockIdx.x, t = threadIdx.x;
  const float* xr = x + (size_t)row * 768;
  float4 v = ((const float4*)xr)[t];
  float s  = v.x + v.y + v.z + v.w;
  float ss = v.x * v.x + v.y * v.y + v.z * v.z + v.w * v.w;
  blockReduce2w3(s, ss, sm);
  float mu  = s * (1.0f / 768.0f);
  float inv = rsqrtf(ss * (1.0f / 768.0f) - mu * mu + LN_EPS);
  float4 gg = ((const float4*)g)[t];
  float4 bb = ((const float4*)b)[t];
  bf16x4 o;
  o[0] = (bf16)((v.x - mu) * inv * gg.x + bb.x);
  o[1] = (bf16)((v.y - mu) * inv * gg.y + bb.y);
  o[2] = (bf16)((v.z - mu) * inv * gg.z + bb.z);
  o[3] = (bf16)((v.w - mu) * inv * gg.w + bb.w);
  ((bf16x4*)(h + (size_t)row * 768))[t] = o;
}

// ================= 256x256 8-phase bf16 GEMM (T2+T3+T4+T5) =================
// A[M][768] x Bt[N][768]^T -> C[M][N].  512 threads = 8 waves (2m x 4n).
// BK=64 -> 12 K-tiles -> 6 iterations x 2 tiles (buf0=even, buf1=odd).
// LDS 128 KiB. T2 swizzle: XOR byte-bits 4-6 with row-bits 0-2.
// Phase rebalance: reads hoisted so ph2/ph4 are read-free; split lgkm in
// ph1/ph3 so second-half LDS service overlaps first MFMA burst.

#define SWZ(x) ((x) ^ ((((x) >> 7) & 7) << 4))

#define SB0 __builtin_amdgcn_sched_barrier(0)
#define BARS do { SB0; __builtin_amdgcn_s_barrier(); SB0; } while (0)
#define LGKM(n) do { asm volatile("s_waitcnt lgkmcnt(" #n ")" ::: "memory"); SB0; } while (0)
#define VMC4 do { SB0; asm volatile("s_waitcnt vmcnt(4)" ::: "memory"); } while (0)
#define PRIO1 __builtin_amdgcn_s_setprio(1)
#define PRIO0 __builtin_amdgcn_s_setprio(0)

#define LDA1(base, mh, i, ks) \
  af[i][ks] = *(const bf16x8*)((base) + SWZ((wm * 128 + ((mh) * 4 + (i)) * 16 + llo) * 128 + (ks) * 64 + lhi * 16))

#define LDB1(base, n, ks) \
  bf[n][ks] = *(const bf16x8*)((base) + SWZ(((((n) >> 1) * 128 + wn * 32 + ((n) & 1) * 16 + llo) * 128 + (ks) * 64 + lhi * 16)))

#define MF1(mh, nh, i, jn, ks) \
  acc[(mh) * 4 + (i)][(nh) * 2 + (jn)] = __builtin_amdgcn_mfma_f32_16x16x32_bf16( \
      af[i][ks], bf[(nh) * 2 + (jn)][ks], acc[(mh) * 4 + (i)][(nh) * 2 + (jn)], 0, 0, 0)
#define MF8(mh, nh, ks) do { \
  MF1(mh, nh, 0, 0, ks); MF1(mh, nh, 0, 1, ks); MF1(mh, nh, 1, 0, ks); MF1(mh, nh, 1, 1, ks); \
  MF1(mh, nh, 2, 0, ks); MF1(mh, nh, 2, 1, ks); MF1(mh, nh, 3, 0, ks); MF1(mh, nh, 3, 1, ks); } while (0)

#define STA(b, q, kt) gl_lds16(A + srcA[q] + (kt) * 64, &As_[b][(q) * 4096 + wave * 512])
#define STB(b, q, kt) gl_lds16(Bt + srcB[q] + (kt) * 64, &Bs_[b][(q) * 4096 + wave * 512])

template <bool OUT_BF16>
__global__ __launch_bounds__(512, 2) void gemm8p(const bf16* __restrict__ A,
                                                 const bf16* __restrict__ Bt,
                                                 void* __restrict__ Cv,
                                                 int Nn, int NBN) {
  __shared__ __align__(16) bf16 As_[2][16384];
  __shared__ __align__(16) bf16 Bs_[2][16384];
  const int tid = threadIdx.x;
  const int wave = tid >> 6, lane = tid & 63;
  const int llo = lane & 15, lhi = lane >> 4;
  const int wm = wave >> 2, wn = wave & 3;

  const int nwg = gridDim.x, bid = blockIdx.x;
  const int wg = (bid & 7) * (nwg >> 3) + (bid >> 3);
  const int rb = wg / NBN, cb = wg - rb * NBN;
  const int brow = rb * 256, bcol = cb * 256;

  // stage source element-offsets per chunk slot (involution pre-swizzle)
  uint32_t srcA[4], srcB[4];
  #pragma unroll
  for (int q = 0; q < 4; ++q) {
    int d = q * 8192 + tid * 16;          // dest byte offset within 32KB tile
    int a = SWZ(d);                       // logical byte offset
    int r = a >> 7, c = (a & 127) >> 1;   // logical row / bf16 col
    srcA[q] = (uint32_t)(brow + r) * GK + c;
    int nh = r >> 7, wnn = (r >> 5) & 3, r32 = r & 31;  // B row permutation
    srcB[q] = (uint32_t)(bcol + wnn * 64 + nh * 32 + r32) * GK + c;
  }

  f32x4 acc[8][4];
  #pragma unroll
  for (int m = 0; m < 8; ++m)
    #pragma unroll
    for (int n = 0; n < 4; ++n) acc[m][n] = (f32x4){0.f, 0.f, 0.f, 0.f};

  bf16x8 af[4][2], bf[4][2];
  const char* As0 = (const char*)&As_[0][0];
  const char* As1 = (const char*)&As_[1][0];
  const char* Bs0 = (const char*)&Bs_[0][0];
  const char* Bs1 = (const char*)&Bs_[1][0];

  // -------- prologue: tile0 full (8), tile1 partial (4); keep 4 in flight
  STA(0, 0, 0); STA(0, 1, 0); STA(0, 2, 0); STA(0, 3, 0);
  STB(0, 0, 0); STB(0, 1, 0); STB(0, 2, 0); STB(0, 3, 0);
  STA(1, 0, 1); STA(1, 2, 1); STB(1, 0, 1); STB(1, 1, 1);
  SB0;
  asm volatile("s_waitcnt vmcnt(4)" ::: "memory");
  __builtin_amdgcn_s_barrier();
  SB0;

  for (int j = 0; j < 6; ++j) {
    const int t1 = 2 * j + 1, t2 = 2 * j + 2, t3 = 2 * j + 3;
    // ---- ph1: all even-tile A-q0 + B reads (ks0 group first); MFQ(0,0)
    LDA1(As0, 0, 0, 0); LDA1(As0, 0, 1, 0); LDA1(As0, 0, 2, 0); LDA1(As0, 0, 3, 0);
    LDB1(Bs0, 0, 0);    LDB1(Bs0, 1, 0);
    SB0;
    LDA1(As0, 0, 0, 1); LDA1(As0, 0, 1, 1); LDA1(As0, 0, 2, 1); LDA1(As0, 0, 3, 1);
    LDB1(Bs0, 0, 1);    LDB1(Bs0, 1, 1);
    SB0;
    LDB1(Bs0, 2, 0); LDB1(Bs0, 3, 0); LDB1(Bs0, 2, 1); LDB1(Bs0, 3, 1);
    STA(1, 1, t1); STA(1, 3, t1);
    BARS;
    LGKM(10); PRIO1; MF8(0, 0, 0);
    LGKM(4);  MF8(0, 0, 1); PRIO0;
    BARS;
    // ---- ph2: read-free; MFQ(0,1)
    STB(1, 2, t1); STB(1, 3, t1);
    BARS;
    LGKM(0); PRIO1; MF8(0, 1, 0); MF8(0, 1, 1); PRIO0;
    BARS;
    // ---- ph3: even-tile A-q1 (ks0 first); MFQ(1,0)
    LDA1(As0, 1, 0, 0); LDA1(As0, 1, 1, 0); LDA1(As0, 1, 2, 0); LDA1(As0, 1, 3, 0);
    SB0;
    LDA1(As0, 1, 0, 1); LDA1(As0, 1, 1, 1); LDA1(As0, 1, 2, 1); LDA1(As0, 1, 3, 1);
    STA(0, 0, t2); STA(0, 2, t2);
    BARS;
    LGKM(4); PRIO1; MF8(1, 0, 0);
    LGKM(0); MF8(1, 0, 1); PRIO0;
    BARS;
    // ---- ph4: read-free; MFQ(1,1); counted vmcnt for odd tile
    STB(0, 0, t2); STB(0, 1, t2);
    BARS;
    PRIO1; MF8(1, 1, 0); MF8(1, 1, 1); PRIO0;
    VMC4;
    BARS;
    // ---- ph5: odd tile A-q0 + B reads; MFQ(0,0)
    LDA1(As1, 0, 0, 0); LDA1(As1, 0, 1, 0); LDA1(As1, 0, 2, 0); LDA1(As1, 0, 3, 0);
    LDB1(Bs1, 0, 0);    LDB1(Bs1, 1, 0);
    SB0;
    LDA1(As1, 0, 0, 1); LDA1(As1, 0, 1, 1); LDA1(As1, 0, 2, 1); LDA1(As1, 0, 3, 1);
    LDB1(Bs1, 0, 1);    LDB1(Bs1, 1, 1);
    SB0;
    LDB1(Bs1, 2, 0); LDB1(Bs1, 3, 0); LDB1(Bs1, 2, 1); LDB1(Bs1, 3, 1);
    STA(0, 1, t2); STA(0, 3, t2);
    BARS;
    LGKM(10); PRIO1; MF8(0, 0, 0);
    LGKM(4);  MF8(0, 0, 1); PRIO0;
    BARS;
    // ---- ph6: read-free; MFQ(0,1)
    STB(0, 2, t2); STB(0, 3, t2);
    BARS;
    LGKM(0); PRIO1; MF8(0, 1, 0); MF8(0, 1, 1); PRIO0;
    BARS;
    // ---- ph7: odd tile A-q1; MFQ(1,0)
    LDA1(As1, 1, 0, 0); LDA1(As1, 1, 1, 0); LDA1(As1, 1, 2, 0); LDA1(As1, 1, 3, 0);
    SB0;
    LDA1(As1, 1, 0, 1); LDA1(As1, 1, 1, 1); LDA1(As1, 1, 2, 1); LDA1(As1, 1, 3, 1);
    STA(1, 0, t3); STA(1, 2, t3);
    BARS;
    LGKM(4); PRIO1; MF8(1, 0, 0);
    LGKM(0); MF8(1, 0, 1); PRIO0;
    BARS;
    // ---- ph8: read-free; MFQ(1,1); counted vmcnt for next even tile
    STB(1, 0, t3); STB(1, 1, t3);
    BARS;
    PRIO1; MF8(1, 1, 0); MF8(1, 1, 1); PRIO0;
    VMC4;
    BARS;
  }

  // -------- epilogue: C write
  #pragma unroll
  for (int m = 0; m < 8; ++m) {
    #pragma unroll
    for (int n = 0; n < 4; ++n) {
      int row = brow + wm * 128 + m * 16 + lhi * 4;
      int col = bcol + wn * 64 + n * 16 + llo;
      #pragma unroll
      for (int r2 = 0; r2 < 4; ++r2) {
        if (OUT_BF16)
          ((bf16*)Cv)[(size_t)(row + r2) * Nn + col] = (bf16)acc[m][n][r2];
        else
          ((float*)Cv)[(size_t)(row + r2) * Nn + col] = acc[m][n][r2];
      }
    }
  }
}

// ---------------- 3a: kv partial sums, k-norm computed inline ----------------
// grid = 8 batches * 32 chunks of 128 tokens; wave w owns 32 tokens.
__global__ __launch_bounds__(256) void kv_partial(const bf16* __restrict__ qkv,
                                                  float* __restrict__ kvp) {
  __shared__ float sm[4][768];
  int b = blockIdx.x >> 5, chunk = blockIdx.x & 31;
  int wave = threadIdx.x >> 6, lane = threadIdx.x & 63;
  const bf16* base = qkv + ((size_t)(b * 4096 + chunk * 128 + wave * 32)) * 2304;
  float acc[3][4] = {};
  for (int i = 0; i < 32; ++i) {
    const bf16* kr = base + (size_t)i * 2304 + 768;
    const bf16* vr = kr + 768;
    bf16x4 k4[3], v4[3];
    #pragma unroll
    for (int c = 0; c < 3; ++c) {
      k4[c] = *(const bf16x4*)(kr + c * 256 + lane * 4);
      v4[c] = *(const bf16x4*)(vr + c * 256 + lane * 4);
    }
    float ssk = 0.f;
    #pragma unroll
    for (int c = 0; c < 3; ++c)
      #pragma unroll
      for (int j = 0; j < 4; ++j) { float kf = (float)k4[c][j]; ssk += kf * kf; }
    #pragma unroll
    for (int off = 32; off > 0; off >>= 1) ssk += __shfl_xor(ssk, off, 64);
    float wi = 1.0f / fmaxf(sqrtf(ssk), NORM_EPS);
    #pragma unroll
    for (int c = 0; c < 3; ++c)
      #pragma unroll
      for (int j = 0; j < 4; ++j)
        acc[c][j] += (float)k4[c][j] * (float)v4[c][j] * wi;
  }
  #pragma unroll
  for (int c = 0; c < 3; ++c)
    #pragma unroll
    for (int j = 0; j < 4; ++j)
      sm[wave][c * 256 + lane * 4 + j] = acc[c][j];
  __syncthreads();
  int t = threadIdx.x;
  #pragma unroll
  for (int c = 0; c < 3; ++c) {
    int e = c * 256 + t;
    kvp[(size_t)blockIdx.x * 768 + e] = sm[0][e] + sm[1][e] + sm[2][e] + sm[3][e];
  }
}

// ---------------- 3b: reduce 32 partials -> kv[8][768] ----------------
__global__ __launch_bounds__(256) void kv_reduce(const float* __restrict__ kvp,
                                                 float* __restrict__ kv) {
  int i = blockIdx.x * 256 + threadIdx.x;   // 0..6143
  int b = i / 768, e = i - b * 768;
  float s = 0.f;
  #pragma unroll
  for (int c = 0; c < 32; ++c) s += kvp[(size_t)(b * 32 + c) * 768 + e];
  kv[i] = s;
}

// ---------------- 4: attn = phi_q * kv (q-norm inline), LN over E -> bf16 ----
// 192 threads = 3 waves
__global__ __launch_bounds__(192) void attn_ln_kernel(const bf16* __restrict__ qkv,
                                                      const float* __restrict__ kv,
                                                      const float* __restrict__ g,
                                                      const float* __restrict__ b,
                                                      bf16* __restrict__ a) {
  __shared__ float sm[6];
  int row = blockIdx.x, t = threadIdx.x;
  int bt = row >> 12;
  const bf16* qr = qkv + (size_t)row * 2304;
  bf16x4 q4 = ((const bf16x4*)qr)[t];
  float q0 = (float)q4[0], q1 = (float)q4[1], q2 = (float)q4[2], q3 = (float)q4[3];
  float sq = q0 * q0 + q1 * q1 + q2 * q2 + q3 * q3, dummy = 0.f;
  blockReduce2w3(sq, dummy, sm);
  float iq = 1.0f / fmaxf(sqrtf(sq), NORM_EPS);
  float4 kv4 = ((const float4*)(kv + bt * 768))[t];
  float4 av;
  av.x = q0 * iq * kv4.x;
  av.y = q1 * iq * kv4.y;
  av.z = q2 * iq * kv4.z;
  av.w = q3 * iq * kv4.w;
  float s  = av.x + av.y + av.z + av.w;
  float ss = av.x * av.x + av.y * av.y + av.z * av.z + av.w * av.w;
  blockReduce2w3(s, ss, sm);
  float mu  = s * (1.0f / 768.0f);
  float inv = rsqrtf(ss * (1.0f / 768.0f) - mu * mu + LN_EPS);
  float4 gg = ((const float4*)g)[t];
  float4 bb = ((const float4*)b)[t];
  bf16x4 o;
  o[0] = (bf16)((av.x - mu) * inv * gg.x + bb.x);
  o[1] = (bf16)((av.y - mu) * inv * gg.y + bb.y);
  o[2] = (bf16)((av.z - mu) * inv * gg.z + bb.z);
  o[3] = (bf16)((av.w - mu) * inv * gg.w + bb.w);
  ((bf16x4*)(a + (size_t)row * 768))[t] = o;
}

// ---------------- launcher ----------------
extern "C" void kernel_launch(void* const* d_in, const int* in_sizes, int n_in,
                              void* d_out, int out_size, void* d_ws, size_t ws_size,
                              hipStream_t stream) {
  const float* x      = (const float*)d_in[0];
  const float* w_qkv  = (const float*)d_in[1];
  const float* w_proj = (const float*)d_in[2];
  const float* g_in   = (const float*)d_in[3];
  const float* b_in   = (const float*)d_in[4];
  const float* g_out  = (const float*)d_in[5];
  const float* b_out  = (const float*)d_in[6];

  char* ws = (char*)d_ws;
  bf16*  wqkvt  = (bf16*)(ws);                              // [2304][768] bf16
  bf16*  wprojt = (bf16*)(ws + 3538944);                    // [768][768]  bf16
  bf16*  h      = (bf16*)(ws + 4718592);                    // [32768][768] bf16 (reused as 'a')
  bf16*  qkv    = (bf16*)(ws + 55050240);                   // [32768][2304] bf16
  float* kvp    = (float*)(ws + 206045184);                 // [8*32][768]
  float* kv     = (float*)(ws + 206831616);                 // [8][768]

  transpose_cvt<<<dim3(2304 / 32, 768 / 32), 256, 0, stream>>>(w_qkv, wqkvt, 768, 2304);
  transpose_cvt<<<dim3(768 / 32, 768 / 32), 256, 0, stream>>>(w_proj, wprojt, 768, 768);
  ln_in_kernel<<<32768, 192, 0, stream>>>(x, g_in, b_in, h);
  gemm8p<true><<<128 * 9, 512, 0, stream>>>(h, wqkvt, (void*)qkv, 2304, 9);
  kv_partial<<<256, 256, 0, stream>>>(qkv, kvp);
  kv_reduce<<<24, 256, 0, stream>>>(kvp, kv);
  attn_ln_kernel<<<32768, 192, 0, stream>>>(qkv, kv, g_out, b_out, h);
  gemm8p<false><<<128 * 3, 512, 0, stream>>>(h, wprojt, d_out, 768, 3);
}